// Round 13
// baseline (2056.097 us; speedup 1.0000x reference)
//
#include <hip/hip_runtime.h>
#include <hip/hip_bf16.h>

#define B_ 2
#define C_ 256
#define NH_ 8
#define D_ 32
#define N_ 4096
#define SCALE_ 0.17677669529663689f
// SCALE * log2(e): folded into Q so softmax is a bare v_exp_f32 per score
#define QSC_ 0.25505277f

typedef __hip_bfloat16 bf16;
typedef __attribute__((ext_vector_type(8))) short sx8;   // 8 bf16 = one MFMA A/B frag
typedef __attribute__((ext_vector_type(4))) short sx4;
typedef __attribute__((ext_vector_type(4))) float fx4;   // MFMA C/D frag
typedef __attribute__((ext_vector_type(4))) int ix4;

__device__ __forceinline__ float b2f(bf16 x) { return __bfloat162float(x); }
__device__ __forceinline__ bf16 f2b(float x) { return __float2bfloat16(x); }
__device__ __forceinline__ short fbs(float x) { bf16 h = __float2bfloat16(x); return *(short*)&h; }
__device__ __forceinline__ float sbf(short s) { bf16 h = *(bf16*)&s; return __bfloat162float(h); }

#if __has_builtin(__builtin_amdgcn_exp2f)
__device__ __forceinline__ float fexp2(float x) { return __builtin_amdgcn_exp2f(x); }
#else
__device__ __forceinline__ float fexp2(float x) { return exp2f(x); }
#endif

// pack two f32 -> one dword of two bf16 by TRUNCATION (1 VALU op via v_perm).
// P in (0,1]; l sums the same truncated values so normalization cancels bias.
__device__ __forceinline__ unsigned pkbf_tr(float x, float y) {
#if __has_builtin(__builtin_amdgcn_perm)
  return __builtin_amdgcn_perm(__builtin_bit_cast(unsigned, y),
                               __builtin_bit_cast(unsigned, x), 0x07060302u);
#else
  unsigned a = __builtin_bit_cast(unsigned, x) >> 16;
  unsigned b = __builtin_bit_cast(unsigned, y) & 0xFFFF0000u;
  return a | b;
#endif
}
// gfx950 MFMA-transpose swaps (VALU cross-lane, not DS pipe) — validated R10
__device__ __forceinline__ void pl32swap(unsigned &a, unsigned &b) {
  asm volatile("v_permlane32_swap_b32 %0, %1" : "+v"(a), "+v"(b));
}
__device__ __forceinline__ void pl16swap(unsigned &a, unsigned &b) {
  asm volatile("v_permlane16_swap_b32 %0, %1" : "+v"(a), "+v"(b));
}

// ---------------------------------------------------------------------------
// Prep (merged): z<4 -> x transpose+convert to xb[z][p][c];
//                z==4 -> weights -> bf16 (wb stacked [wq;wk;wv], wob).
// grid (N_/64, C_/64, 5), block 256
// ---------------------------------------------------------------------------
__global__ __launch_bounds__(256)
void convert_kernel(const float* __restrict__ spatial,
                    const float* __restrict__ freq,
                    const float* __restrict__ wq, const float* __restrict__ wk,
                    const float* __restrict__ wv, const float* __restrict__ wo,
                    bf16* __restrict__ xb, bf16* __restrict__ wb,
                    bf16* __restrict__ wob) {
  const int tid = threadIdx.x;
  if (blockIdx.z == 4) {
    int base = (blockIdx.y * 64 + blockIdx.x) * 256 + tid;   // 0..65535
    #pragma unroll
    for (int i = 0; i < 4; ++i) {
      int idx = base + i * 65536;                            // 0..262143
      if (idx < 196608) {
        const float* src = (idx < 65536) ? wq : (idx < 131072) ? wk : wv;
        wb[idx] = f2b(src[idx & 65535]);
      } else {
        wob[idx - 196608] = f2b(wo[idx - 196608]);
      }
    }
    return;
  }

  const int p0 = blockIdx.x * 64;
  const int c0 = blockIdx.y * 64;
  const int z  = blockIdx.z;            // s*B_ + b
  const int s = z >> 1, b = z & 1;
  const float* x = (s == 0) ? spatial : freq;

  __shared__ float ls[64][65];

  const int pp = tid & 63, cb = tid >> 6;
  #pragma unroll
  for (int i = 0; i < 16; ++i) {
    int c = cb + 4 * i;
    ls[c][pp] = x[(size_t)(b * C_ + c0 + c) * N_ + p0 + pp];
  }
  __syncthreads();

  #pragma unroll
  for (int i = 0; i < 2; ++i) {
    int j = tid + 256 * i;              // 0..511
    int p = j >> 3, ck = (j & 7) * 8;
    short tmp[8];
    #pragma unroll
    for (int u = 0; u < 8; ++u) tmp[u] = fbs(ls[ck + u][p]);
    *(sx8*)(xb + ((size_t)z * N_ + p0 + p) * C_ + c0 + ck) = *(sx8*)tmp;
  }
}

// ---------------------------------------------------------------------------
// Kernel 1: QKV projection as MFMA GEMM. D = W (768x256) * x (256x4096) per z.
//   qhf/khf: per-head pos-major [z][h][n][d32]   (Q pre-scaled by QSC_)
//   vhf:     frag-blocked [z][h][n>>5][d>>4][d&15][n&31]
// grid (N_/128, 768/128, 2*B_), block 256 (4 waves, each 64x64)
// ---------------------------------------------------------------------------
__global__ __launch_bounds__(256)
void qkv_gemm_kernel(const bf16* __restrict__ wb, const bf16* __restrict__ xb,
                     const float* __restrict__ bq, const float* __restrict__ bk,
                     const float* __restrict__ bv,
                     bf16* __restrict__ qhf, bf16* __restrict__ khf,
                     bf16* __restrict__ vhf) {
  const int tid = threadIdx.x;
  const int p0 = blockIdx.x * 128;
  const int o0 = blockIdx.y * 128;
  const int z  = blockIdx.z;

  const int lane = tid & 63, w = tid >> 6;
  const int ml = lane & 15, Q4 = (lane >> 4) * 4, Q8 = (lane >> 4) * 8;
  const int ow = (w >> 1) * 64, pw = (w & 1) * 64;

  __shared__ __align__(16) short asb[128 * 72];
  __shared__ __align__(16) short bsb[128 * 72];
  __shared__ float bias_s[128];

  if (tid < 128) {
    int o = o0 + tid;
    bias_s[tid] = (o < 256) ? bq[o] : (o < 512) ? bk[o - 256] : bv[o - 512];
  }

  const fx4 z4 = {0.f, 0.f, 0.f, 0.f};
  fx4 acc[4][4];
  #pragma unroll
  for (int ot = 0; ot < 4; ++ot)
    #pragma unroll
    for (int pt = 0; pt < 4; ++pt) acc[ot][pt] = z4;

  const int sr = tid >> 1, scu = (tid & 1) * 32;
  for (int k0 = 0; k0 < 256; k0 += 64) {
    __syncthreads();
    #pragma unroll
    for (int u = 0; u < 4; ++u) {
      *(sx8*)&asb[sr * 72 + scu + u * 8] =
          *(const sx8*)&wb[(o0 + sr) * 256 + k0 + scu + u * 8];
      *(sx8*)&bsb[sr * 72 + scu + u * 8] =
          *(const sx8*)(xb + ((size_t)z * N_ + p0 + sr) * C_ + k0 + scu + u * 8);
    }
    __syncthreads();
    #pragma unroll
    for (int kk = 0; kk < 2; ++kk) {
      sx8 af[4], bfr[4];
      #pragma unroll
      for (int t = 0; t < 4; ++t)
        af[t] = *(sx8*)&asb[(ow + t * 16 + ml) * 72 + kk * 32 + Q8];
      #pragma unroll
      for (int t = 0; t < 4; ++t)
        bfr[t] = *(sx8*)&bsb[(pw + t * 16 + ml) * 72 + kk * 32 + Q8];
      #pragma unroll
      for (int ot = 0; ot < 4; ++ot)
        #pragma unroll
        for (int pt = 0; pt < 4; ++pt)
          acc[ot][pt] = __builtin_amdgcn_mfma_f32_16x16x32_bf16(
              af[ot], bfr[pt], acc[ot][pt], 0, 0, 0);
    }
  }

  if (o0 < 512) {
    bf16* dst = (o0 < 256) ? qhf : khf;
    const int ob = (o0 < 256) ? o0 : o0 - 256;
    const float scl = (o0 < 256) ? QSC_ : 1.f;
    #pragma unroll
    for (int ot = 0; ot < 4; ++ot) {
      const int og = ob + ow + ot * 16 + Q4;    // global o, head = og>>5
      #pragma unroll
      for (int pt = 0; pt < 4; ++pt) {
        int p = p0 + pw + pt * 16 + ml;
        short tmp[4];
        #pragma unroll
        for (int r = 0; r < 4; ++r)
          tmp[r] = fbs((acc[ot][pt][r] + bias_s[ow + ot * 16 + Q4 + r]) * scl);
        *(sx4*)(dst + (((size_t)z * NH_ + (og >> 5)) * N_ + p) * D_ + (og & 31)) =
            *(sx4*)tmp;
      }
    }
  } else {
    #pragma unroll
    for (int ot = 0; ot < 4; ++ot)
      #pragma unroll
      for (int pt = 0; pt < 4; ++pt) {
        int p = p0 + pw + pt * 16 + ml;
        #pragma unroll
        for (int r = 0; r < 4; ++r) {
          int lo = ow + ot * 16 + Q4 + r;       // local o in [0,128)
          int rho = (o0 - 512) + lo;            // 0..255
          int h = rho >> 5, d = rho & 31;
          size_t basev = ((size_t)z * NH_ + h) * D_ * N_;
          vhf[basev + (size_t)(((p >> 5) * 2) + (d >> 4)) * 512 +
              (d & 15) * 32 + (p & 31)] = f2b(acc[ot][pt][r] + bias_s[lo]);
        }
      }
  }
}

// ---------------------------------------------------------------------------
// Kernel 2: MFMA flash attention. Q-tile 256 (4 strips/wave) so each K/V
// fragment read from LDS is amortized over 2x the queries of R12 (halves the
// LDS frag-read traffic per score). Strip order rotated by wave id so waves
// sit in different QK/exp/PV phases (breaks barrier phase-lockstep).
// P^T -> B-operand in registers via v_permlane{32,16}_swap; P packed by
// v_perm truncation; max-free softmax; l via ones-row MFMA.
// grid (N_/256, NH_, 4), block 256 (4 waves, 64 q each)
// ---------------------------------------------------------------------------
__global__ __launch_bounds__(256, 2)
void attn_kernel(const bf16* __restrict__ qhf, const bf16* __restrict__ khf,
                 const bf16* __restrict__ vhf, bf16* __restrict__ attoT) {
  const int tid  = threadIdx.x;
  const int m0   = blockIdx.x * 256;
  const int h    = blockIdx.y;
  const int z    = blockIdx.z;          // s*B_ + b
  const int s = z >> 1, b = z & 1;
  const int zo = ((1 - s) << 1) | b;    // kv source

  const bf16* qz = qhf + ((size_t)z  * NH_ + h) * N_ * D_;
  const bf16* kz = khf + ((size_t)zo * NH_ + h) * N_ * D_;
  const bf16* vz = vhf + ((size_t)zo * NH_ + h) * D_ * N_;

  const int lane = tid & 63;
  const int w    = tid >> 6;
  const int ml   = lane & 15;
  const int q4   = lane >> 4;           // quad 0..3
  const int Q4   = q4 * 4;
  const int Q8   = q4 * 8;

  // double-buffered 64-key K/V tiles
  __shared__ __align__(16) short kts[2][64 * 32];       // 8 KB (XOR-swizzled)
  __shared__ __align__(16) short vss[2][4][16 * 36];    // 9 KB

  // Q fragments (B-operand): strip s4 -> row m0 + w*64 + s4*16 + ml
  sx8 qf[4];
  #pragma unroll
  for (int s4 = 0; s4 < 4; ++s4)
    qf[s4] = *(const sx8*)(qz + (size_t)(m0 + w * 64 + s4 * 16 + ml) * D_ + Q8);

  sx8 onesf;                            // bf16 1.0 row for the l-sum MFMA
  #pragma unroll
  for (int u = 0; u < 8; ++u) onesf[u] = (short)0x3F80;

  const fx4 z4 = {0.f, 0.f, 0.f, 0.f};
  fx4 acc[4][2];
  #pragma unroll
  for (int s4 = 0; s4 < 4; ++s4) { acc[s4][0] = z4; acc[s4][1] = z4; }
  fx4 lacc[4] = {z4, z4, z4, z4};

  // staging coords (lane-constant swizzles)
  const int srow = tid >> 2;                              // K: row n 0..63
  const int ksw  = ((tid & 3) ^ (srow & 3)) * 8;          // phys d-granule
  const int vblk = tid >> 6, vrow = (tid >> 2) & 15, vg = (tid & 3) * 8;
  const int kfg  = (q4 ^ (ml & 3)) * 8;                   // kts read granule

  sx8 kpre = *(const sx8*)(kz + (size_t)tid * 8);
  sx8 vpre = *(const sx8*)(vz + (size_t)tid * 8);
  *(sx8*)&kts[0][srow * 32 + ksw] = kpre;
  *(sx8*)&vss[0][vblk][vrow * 36 + vg] = vpre;
  __syncthreads();

  int cur = 0;
  for (int n0 = 0; n0 < N_; n0 += 64) {
    const bool more = (n0 + 64 < N_);
    if (more) {
      kpre = *(const sx8*)(kz + (size_t)(n0 + 64) * D_ + (size_t)tid * 8);
      vpre = *(const sx8*)(vz + (size_t)(n0 + 64) * D_ + (size_t)tid * 8);
    }

    // fragments from LDS (shared across all 4 strips)
    sx8 kf[4], vf[2][2];
    #pragma unroll
    for (int t = 0; t < 4; ++t)
      kf[t] = *(sx8*)&kts[cur][(t * 16 + ml) * 32 + kfg];
    #pragma unroll
    for (int dt = 0; dt < 2; ++dt)
      #pragma unroll
      for (int c = 0; c < 2; ++c)
        vf[dt][c] = *(sx8*)&vss[cur][c * 2 + dt][ml * 36 + Q8];

    // strip loop, rotated by wave id to de-phase the 4 waves
    #pragma unroll
    for (int s0 = 0; s0 < 4; ++s0) {
      const int s4 = (s0 + w) & 3;
      fx4 st[4];
      #pragma unroll
      for (int t = 0; t < 4; ++t)
        st[t] = __builtin_amdgcn_mfma_f32_16x16x32_bf16(kf[t], qf[s4], z4, 0, 0, 0);

      // exp + truncate-pack each tile's 4 values into 2 dwords
      unsigned T[4][2];
      #pragma unroll
      for (int t = 0; t < 4; ++t) {
        float e0 = fexp2(st[t][0]), e1 = fexp2(st[t][1]);
        float e2 = fexp2(st[t][2]), e3 = fexp2(st[t][3]);
        T[t][0] = pkbf_tr(e0, e1);
        T[t][1] = pkbf_tr(e2, e3);
      }
      // in-register C-layout -> B-operand transform (validated R10)
      pl32swap(T[0][0], T[1][0]); pl16swap(T[0][0], T[1][0]);
      pl32swap(T[0][1], T[1][1]); pl16swap(T[0][1], T[1][1]);
      pl32swap(T[2][0], T[3][0]); pl16swap(T[2][0], T[3][0]);
      pl32swap(T[2][1], T[3][1]); pl16swap(T[2][1], T[3][1]);
      ix4 p0 = {(int)T[0][0], (int)T[0][1], (int)T[1][0], (int)T[1][1]};
      ix4 p1 = {(int)T[2][0], (int)T[2][1], (int)T[3][0], (int)T[3][1]};
      sx8 pf0 = *(sx8*)&p0;
      sx8 pf1 = *(sx8*)&p1;

      lacc[s4] = __builtin_amdgcn_mfma_f32_16x16x32_bf16(onesf, pf0, lacc[s4], 0, 0, 0);
      lacc[s4] = __builtin_amdgcn_mfma_f32_16x16x32_bf16(onesf, pf1, lacc[s4], 0, 0, 0);
      #pragma unroll
      for (int dt = 0; dt < 2; ++dt) {
        fx4 a = acc[s4][dt];
        a = __builtin_amdgcn_mfma_f32_16x16x32_bf16(vf[dt][0], pf0, a, 0, 0, 0);
        a = __builtin_amdgcn_mfma_f32_16x16x32_bf16(vf[dt][1], pf1, a, 0, 0, 0);
        acc[s4][dt] = a;
      }
    }

    // write prefetched next tile into the idle buffer, then ONE barrier
    if (more) {
      *(sx8*)&kts[cur ^ 1][srow * 32 + ksw] = kpre;
      *(sx8*)&vss[cur ^ 1][vblk][vrow * 36 + vg] = vpre;
    }
    __syncthreads();
    cur ^= 1;
  }

  // epilogue: l for this lane's query column is lacc[s4][0] (all rows equal)
  #pragma unroll
  for (int s4 = 0; s4 < 4; ++s4) {
    float inv = 1.f / lacc[s4][0];
    int col = m0 + w * 64 + s4 * 16 + ml;
    #pragma unroll
    for (int dt = 0; dt < 2; ++dt) {
      short tmp[4];
      #pragma unroll
      for (int r = 0; r < 4; ++r) tmp[r] = fbs(acc[s4][dt][r] * inv);
      *(sx4*)(attoT + ((size_t)z * N_ + col) * C_ + h * D_ + dt * 16 + Q4) =
          *(sx4*)tmp;
    }
  }
}

// ---------------------------------------------------------------------------
// Kernel 3: out_proj as MFMA GEMM. D = Wo * (attS + attF), residuals fused.
// ---------------------------------------------------------------------------
__global__ __launch_bounds__(256)
void out_proj_kernel(const bf16* __restrict__ wob, const bf16* __restrict__ attoT,
                     const float* __restrict__ spatial,
                     const float* __restrict__ freq,
                     const float* __restrict__ bo, float* __restrict__ out) {
  const int tid = threadIdx.x;
  const int p0 = blockIdx.x * 128;
  const int o0 = blockIdx.y * 64;
  const int b  = blockIdx.z;

  const int lane = tid & 63, w = tid >> 6;
  const int ml = lane & 15, Q4 = (lane >> 4) * 4, Q8 = (lane >> 4) * 8;
  const int ow = (w >> 1) * 32, pw = (w & 1) * 64;

  __shared__ __align__(16) short asb[64 * 72];
  __shared__ __align__(16) short bsb[128 * 72];
  __shared__ float bo_s[64];

  if (tid < 64) bo_s[tid] = 2.f * bo[o0 + tid];

  const bf16* at0 = attoT + (size_t)(0 + b) * N_ * C_;   // s=0 slice
  const bf16* at1 = attoT + (size_t)(2 + b) * N_ * C_;   // s=1 slice

  const fx4 z4 = {0.f, 0.f, 0.f, 0.f};
  fx4 acc[2][4];
  #pragma unroll
  for (int ot = 0; ot < 2; ++ot)
    #pragma unroll
    for (int pt = 0; pt < 4; ++pt) acc[ot][pt] = z4;

  for (int k0 = 0; k0 < 256; k0 += 64) {
    __syncthreads();
    #pragma unroll
    for (int i = 0; i < 2; ++i) {
      int j = tid + 256 * i;            // 0..511
      int r = j >> 3, cu = (j & 7) * 8;
      *(sx8*)&asb[r * 72 + cu] = *(const sx8*)&wob[(o0 + r) * 256 + k0 + cu];
    }
    #pragma unroll
    for (int i = 0; i < 4; ++i) {
      int j = tid + 256 * i;            // 0..1023
      int p = j >> 3, cu = (j & 7) * 8;
      sx8 va = *(const sx8*)(at0 + (size_t)(p0 + p) * C_ + k0 + cu);
      sx8 vb2 = *(const sx8*)(at1 + (size_t)(p0 + p) * C_ + k0 + cu);
      short tmp[8];
      #pragma unroll
      for (int u = 0; u < 8; ++u) tmp[u] = fbs(sbf(va[u]) + sbf(vb2[u]));
      *(sx8*)&bsb[p * 72 + cu] = *(sx8*)tmp;
    }
    __syncthreads();
    #pragma unroll
    for (int kk = 0; kk < 2; ++kk) {
      sx8 af[2], bfr[4];
      #pragma unroll
      for (int t = 0; t < 2; ++t)
        af[t] = *(sx8*)&asb[(ow + t * 16 + ml) * 72 + kk * 32 + Q8];
      #pragma unroll
      for (int t = 0; t < 4; ++t)
        bfr[t] = *(sx8*)&bsb[(pw + t * 16 + ml) * 72 + kk * 32 + Q8];
      #pragma unroll
      for (int ot = 0; ot < 2; ++ot)
        #pragma unroll
        for (int pt = 0; pt < 4; ++pt)
          acc[ot][pt] = __builtin_amdgcn_mfma_f32_16x16x32_bf16(
              af[ot], bfr[pt], acc[ot][pt], 0, 0, 0);
    }
  }

  #pragma unroll
  for (int ot = 0; ot < 2; ++ot)
    #pragma unroll
    for (int pt = 0; pt < 4; ++pt) {
      int p = p0 + pw + pt * 16 + ml;
      #pragma unroll
      for (int r = 0; r < 4; ++r) {
        int ol = ow + ot * 16 + Q4 + r;
        size_t off = ((size_t)b * C_ + o0 + ol) * N_ + p;
        out[off] = acc[ot][pt][r] + bo_s[ol] + spatial[off] + freq[off];
      }
    }
}

extern "C" void kernel_launch(void* const* d_in, const int* in_sizes, int n_in,
                              void* d_out, int out_size, void* d_ws, size_t ws_size,
                              hipStream_t stream) {
  const float* spatial = (const float*)d_in[0];
  const float* freq    = (const float*)d_in[1];
  const float* wq = (const float*)d_in[2];
  const float* bq = (const float*)d_in[3];
  const float* wk = (const float*)d_in[4];
  const float* bk = (const float*)d_in[5];
  const float* wv = (const float*)d_in[6];
  const float* bv = (const float*)d_in[7];
  const float* wo = (const float*)d_in[8];
  const float* bo = (const float*)d_in[9];
  float* out = (float*)d_out;

  // workspace layout (bf16 elements)
  const size_t SZ = (size_t)2 * B_ * N_ * C_;   // 4.19M elems = 8.4 MB
  bf16* xb    = (bf16*)d_ws;                    // [z][p][c]
  bf16* qhf   = xb + SZ;                        // [z][h][n][d]
  bf16* khf   = qhf + SZ;                       // [z][h][n][d]
  bf16* vhf   = khf + SZ;                       // [z][h] frag-blocked
  bf16* attoT = vhf + SZ;                       // [z][p][c]
  bf16* wb    = attoT + SZ;                     // [768][256]
  bf16* wob   = wb + 768 * 256;                 // [256][256]

  convert_kernel<<<dim3(N_ / 64, C_ / 64, 5), 256, 0, stream>>>(
      spatial, freq, wq, wk, wv, wo, xb, wb, wob);
  qkv_gemm_kernel<<<dim3(N_ / 128, 768 / 128, 2 * B_), 256, 0, stream>>>(
      wb, xb, bq, bk, bv, qhf, khf, vhf);
  attn_kernel<<<dim3(N_ / 256, NH_, 2 * B_), 256, 0, stream>>>(
      qhf, khf, vhf, attoT);
  out_proj_kernel<<<dim3(N_ / 128, C_ / 64, B_), 256, 0, stream>>>(
      wob, attoT, spatial, freq, bo, out);
}

// Round 14
// 205.431 us; speedup vs baseline: 10.0087x; 10.0087x over previous
//
#include <hip/hip_runtime.h>
#include <hip/hip_bf16.h>

#define B_ 2
#define C_ 256
#define NH_ 8
#define D_ 32
#define N_ 4096
#define SCALE_ 0.17677669529663689f
// SCALE * log2(e): folded into Q so softmax is a bare v_exp_f32 per score
#define QSC_ 0.25505277f

typedef __hip_bfloat16 bf16;
typedef __attribute__((ext_vector_type(8))) short sx8;   // 8 bf16 = one MFMA A/B frag
typedef __attribute__((ext_vector_type(4))) short sx4;
typedef __attribute__((ext_vector_type(4))) float fx4;   // MFMA C/D frag
typedef __attribute__((ext_vector_type(4))) int ix4;

__device__ __forceinline__ float b2f(bf16 x) { return __bfloat162float(x); }
__device__ __forceinline__ bf16 f2b(float x) { return __float2bfloat16(x); }
__device__ __forceinline__ short fbs(float x) { bf16 h = __float2bfloat16(x); return *(short*)&h; }
__device__ __forceinline__ float sbf(short s) { bf16 h = *(bf16*)&s; return __bfloat162float(h); }

#if __has_builtin(__builtin_amdgcn_exp2f)
__device__ __forceinline__ float fexp2(float x) { return __builtin_amdgcn_exp2f(x); }
#else
__device__ __forceinline__ float fexp2(float x) { return exp2f(x); }
#endif

// pack two f32 -> one dword of two bf16 by TRUNCATION (1 VALU op via v_perm).
// P in (0,1]; l sums the same truncated values so normalization cancels bias.
__device__ __forceinline__ unsigned pkbf_tr(float x, float y) {
#if __has_builtin(__builtin_amdgcn_perm)
  return __builtin_amdgcn_perm(__builtin_bit_cast(unsigned, y),
                               __builtin_bit_cast(unsigned, x), 0x07060302u);
#else
  unsigned a = __builtin_bit_cast(unsigned, x) >> 16;
  unsigned b = __builtin_bit_cast(unsigned, y) & 0xFFFF0000u;
  return a | b;
#endif
}
// gfx950 MFMA-transpose swaps (VALU cross-lane, not DS pipe) — validated R10
__device__ __forceinline__ void pl32swap(unsigned &a, unsigned &b) {
  asm volatile("v_permlane32_swap_b32 %0, %1" : "+v"(a), "+v"(b));
}
__device__ __forceinline__ void pl16swap(unsigned &a, unsigned &b) {
  asm volatile("v_permlane16_swap_b32 %0, %1" : "+v"(a), "+v"(b));
}

// ---------------------------------------------------------------------------
// Prep (merged): z<4 -> x transpose+convert to xb[z][p][c];
//                z==4 -> weights -> bf16 (wb stacked [wq;wk;wv], wob).
// grid (N_/64, C_/64, 5), block 256
// ---------------------------------------------------------------------------
__global__ __launch_bounds__(256)
void convert_kernel(const float* __restrict__ spatial,
                    const float* __restrict__ freq,
                    const float* __restrict__ wq, const float* __restrict__ wk,
                    const float* __restrict__ wv, const float* __restrict__ wo,
                    bf16* __restrict__ xb, bf16* __restrict__ wb,
                    bf16* __restrict__ wob) {
  const int tid = threadIdx.x;
  if (blockIdx.z == 4) {
    int base = (blockIdx.y * 64 + blockIdx.x) * 256 + tid;   // 0..65535
    #pragma unroll
    for (int i = 0; i < 4; ++i) {
      int idx = base + i * 65536;                            // 0..262143
      if (idx < 196608) {
        const float* src = (idx < 65536) ? wq : (idx < 131072) ? wk : wv;
        wb[idx] = f2b(src[idx & 65535]);
      } else {
        wob[idx - 196608] = f2b(wo[idx - 196608]);
      }
    }
    return;
  }

  const int p0 = blockIdx.x * 64;
  const int c0 = blockIdx.y * 64;
  const int z  = blockIdx.z;            // s*B_ + b
  const int s = z >> 1, b = z & 1;
  const float* x = (s == 0) ? spatial : freq;

  __shared__ float ls[64][65];

  const int pp = tid & 63, cb = tid >> 6;
  #pragma unroll
  for (int i = 0; i < 16; ++i) {
    int c = cb + 4 * i;
    ls[c][pp] = x[(size_t)(b * C_ + c0 + c) * N_ + p0 + pp];
  }
  __syncthreads();

  #pragma unroll
  for (int i = 0; i < 2; ++i) {
    int j = tid + 256 * i;              // 0..511
    int p = j >> 3, ck = (j & 7) * 8;
    short tmp[8];
    #pragma unroll
    for (int u = 0; u < 8; ++u) tmp[u] = fbs(ls[ck + u][p]);
    *(sx8*)(xb + ((size_t)z * N_ + p0 + p) * C_ + c0 + ck) = *(sx8*)tmp;
  }
}

// ---------------------------------------------------------------------------
// Kernel 1: QKV projection as MFMA GEMM. D = W (768x256) * x (256x4096) per z.
//   qhf/khf: per-head pos-major [z][h][n][d32]   (Q pre-scaled by QSC_)
//   vhf:     frag-blocked [z][h][n>>5][d>>4][d&15][n&31]
// grid (N_/128, 768/128, 2*B_), block 256 (4 waves, each 64x64)
// ---------------------------------------------------------------------------
__global__ __launch_bounds__(256)
void qkv_gemm_kernel(const bf16* __restrict__ wb, const bf16* __restrict__ xb,
                     const float* __restrict__ bq, const float* __restrict__ bk,
                     const float* __restrict__ bv,
                     bf16* __restrict__ qhf, bf16* __restrict__ khf,
                     bf16* __restrict__ vhf) {
  const int tid = threadIdx.x;
  const int p0 = blockIdx.x * 128;
  const int o0 = blockIdx.y * 128;
  const int z  = blockIdx.z;

  const int lane = tid & 63, w = tid >> 6;
  const int ml = lane & 15, Q4 = (lane >> 4) * 4, Q8 = (lane >> 4) * 8;
  const int ow = (w >> 1) * 64, pw = (w & 1) * 64;

  __shared__ __align__(16) short asb[128 * 72];
  __shared__ __align__(16) short bsb[128 * 72];
  __shared__ float bias_s[128];

  if (tid < 128) {
    int o = o0 + tid;
    bias_s[tid] = (o < 256) ? bq[o] : (o < 512) ? bk[o - 256] : bv[o - 512];
  }

  const fx4 z4 = {0.f, 0.f, 0.f, 0.f};
  fx4 acc[4][4];
  #pragma unroll
  for (int ot = 0; ot < 4; ++ot)
    #pragma unroll
    for (int pt = 0; pt < 4; ++pt) acc[ot][pt] = z4;

  const int sr = tid >> 1, scu = (tid & 1) * 32;
  for (int k0 = 0; k0 < 256; k0 += 64) {
    __syncthreads();
    #pragma unroll
    for (int u = 0; u < 4; ++u) {
      *(sx8*)&asb[sr * 72 + scu + u * 8] =
          *(const sx8*)&wb[(o0 + sr) * 256 + k0 + scu + u * 8];
      *(sx8*)&bsb[sr * 72 + scu + u * 8] =
          *(const sx8*)(xb + ((size_t)z * N_ + p0 + sr) * C_ + k0 + scu + u * 8);
    }
    __syncthreads();
    #pragma unroll
    for (int kk = 0; kk < 2; ++kk) {
      sx8 af[4], bfr[4];
      #pragma unroll
      for (int t = 0; t < 4; ++t)
        af[t] = *(sx8*)&asb[(ow + t * 16 + ml) * 72 + kk * 32 + Q8];
      #pragma unroll
      for (int t = 0; t < 4; ++t)
        bfr[t] = *(sx8*)&bsb[(pw + t * 16 + ml) * 72 + kk * 32 + Q8];
      #pragma unroll
      for (int ot = 0; ot < 4; ++ot)
        #pragma unroll
        for (int pt = 0; pt < 4; ++pt)
          acc[ot][pt] = __builtin_amdgcn_mfma_f32_16x16x32_bf16(
              af[ot], bfr[pt], acc[ot][pt], 0, 0, 0);
    }
  }

  if (o0 < 512) {
    bf16* dst = (o0 < 256) ? qhf : khf;
    const int ob = (o0 < 256) ? o0 : o0 - 256;
    const float scl = (o0 < 256) ? QSC_ : 1.f;
    #pragma unroll
    for (int ot = 0; ot < 4; ++ot) {
      const int og = ob + ow + ot * 16 + Q4;    // global o, head = og>>5
      #pragma unroll
      for (int pt = 0; pt < 4; ++pt) {
        int p = p0 + pw + pt * 16 + ml;
        short tmp[4];
        #pragma unroll
        for (int r = 0; r < 4; ++r)
          tmp[r] = fbs((acc[ot][pt][r] + bias_s[ow + ot * 16 + Q4 + r]) * scl);
        *(sx4*)(dst + (((size_t)z * NH_ + (og >> 5)) * N_ + p) * D_ + (og & 31)) =
            *(sx4*)tmp;
      }
    }
  } else {
    #pragma unroll
    for (int ot = 0; ot < 4; ++ot)
      #pragma unroll
      for (int pt = 0; pt < 4; ++pt) {
        int p = p0 + pw + pt * 16 + ml;
        #pragma unroll
        for (int r = 0; r < 4; ++r) {
          int lo = ow + ot * 16 + Q4 + r;       // local o in [0,128)
          int rho = (o0 - 512) + lo;            // 0..255
          int h = rho >> 5, d = rho & 31;
          size_t basev = ((size_t)z * NH_ + h) * D_ * N_;
          vhf[basev + (size_t)(((p >> 5) * 2) + (d >> 4)) * 512 +
              (d & 15) * 32 + (p & 31)] = f2b(acc[ot][pt][r] + bias_s[lo]);
        }
      }
  }
}

// ---------------------------------------------------------------------------
// Kernel 2: MFMA flash attention. Q-tile 256 (4 strips/wave, STATIC order —
// R13's wave-rotated index demoted acc/qf/lacc to scratch, 18x regression).
// Each K/V fragment read amortized over 64 queries (2x R12).
// P^T -> B-operand in registers via v_permlane{32,16}_swap; P packed by
// v_perm truncation; max-free softmax; l via ones-row MFMA.
// grid (N_/256, NH_, 4), block 256 (4 waves, 64 q each)
// ---------------------------------------------------------------------------
__global__ __launch_bounds__(256, 2)
void attn_kernel(const bf16* __restrict__ qhf, const bf16* __restrict__ khf,
                 const bf16* __restrict__ vhf, bf16* __restrict__ attoT) {
  const int tid  = threadIdx.x;
  const int m0   = blockIdx.x * 256;
  const int h    = blockIdx.y;
  const int z    = blockIdx.z;          // s*B_ + b
  const int s = z >> 1, b = z & 1;
  const int zo = ((1 - s) << 1) | b;    // kv source

  const bf16* qz = qhf + ((size_t)z  * NH_ + h) * N_ * D_;
  const bf16* kz = khf + ((size_t)zo * NH_ + h) * N_ * D_;
  const bf16* vz = vhf + ((size_t)zo * NH_ + h) * D_ * N_;

  const int lane = tid & 63;
  const int w    = tid >> 6;
  const int ml   = lane & 15;
  const int q4   = lane >> 4;           // quad 0..3
  const int Q4   = q4 * 4;
  const int Q8   = q4 * 8;

  // double-buffered 64-key K/V tiles
  __shared__ __align__(16) short kts[2][64 * 32];       // 8 KB (XOR-swizzled)
  __shared__ __align__(16) short vss[2][4][16 * 36];    // 9 KB

  // Q fragments (B-operand): strip s4 -> row m0 + w*64 + s4*16 + ml
  sx8 qf[4];
  #pragma unroll
  for (int s4 = 0; s4 < 4; ++s4)
    qf[s4] = *(const sx8*)(qz + (size_t)(m0 + w * 64 + s4 * 16 + ml) * D_ + Q8);

  sx8 onesf;                            // bf16 1.0 row for the l-sum MFMA
  #pragma unroll
  for (int u = 0; u < 8; ++u) onesf[u] = (short)0x3F80;

  const fx4 z4 = {0.f, 0.f, 0.f, 0.f};
  fx4 acc[4][2];
  #pragma unroll
  for (int s4 = 0; s4 < 4; ++s4) { acc[s4][0] = z4; acc[s4][1] = z4; }
  fx4 lacc[4] = {z4, z4, z4, z4};

  // staging coords (lane-constant swizzles)
  const int srow = tid >> 2;                              // K: row n 0..63
  const int ksw  = ((tid & 3) ^ (srow & 3)) * 8;          // phys d-granule
  const int vblk = tid >> 6, vrow = (tid >> 2) & 15, vg = (tid & 3) * 8;
  const int kfg  = (q4 ^ (ml & 3)) * 8;                   // kts read granule

  sx8 kpre = *(const sx8*)(kz + (size_t)tid * 8);
  sx8 vpre = *(const sx8*)(vz + (size_t)tid * 8);
  *(sx8*)&kts[0][srow * 32 + ksw] = kpre;
  *(sx8*)&vss[0][vblk][vrow * 36 + vg] = vpre;
  __syncthreads();

  int cur = 0;
  for (int n0 = 0; n0 < N_; n0 += 64) {
    const bool more = (n0 + 64 < N_);
    if (more) {
      kpre = *(const sx8*)(kz + (size_t)(n0 + 64) * D_ + (size_t)tid * 8);
      vpre = *(const sx8*)(vz + (size_t)(n0 + 64) * D_ + (size_t)tid * 8);
    }

    // fragments from LDS (shared across all 4 strips)
    sx8 kf[4], vf[2][2];
    #pragma unroll
    for (int t = 0; t < 4; ++t)
      kf[t] = *(sx8*)&kts[cur][(t * 16 + ml) * 32 + kfg];
    #pragma unroll
    for (int dt = 0; dt < 2; ++dt)
      #pragma unroll
      for (int c = 0; c < 2; ++c)
        vf[dt][c] = *(sx8*)&vss[cur][c * 2 + dt][ml * 36 + Q8];

    // strip loop (STATIC index — keeps acc/qf/lacc in registers)
    #pragma unroll
    for (int s4 = 0; s4 < 4; ++s4) {
      fx4 st[4];
      #pragma unroll
      for (int t = 0; t < 4; ++t)
        st[t] = __builtin_amdgcn_mfma_f32_16x16x32_bf16(kf[t], qf[s4], z4, 0, 0, 0);

      // exp + truncate-pack each tile's 4 values into 2 dwords
      unsigned T[4][2];
      #pragma unroll
      for (int t = 0; t < 4; ++t) {
        float e0 = fexp2(st[t][0]), e1 = fexp2(st[t][1]);
        float e2 = fexp2(st[t][2]), e3 = fexp2(st[t][3]);
        T[t][0] = pkbf_tr(e0, e1);
        T[t][1] = pkbf_tr(e2, e3);
      }
      // in-register C-layout -> B-operand transform (validated R10)
      pl32swap(T[0][0], T[1][0]); pl16swap(T[0][0], T[1][0]);
      pl32swap(T[0][1], T[1][1]); pl16swap(T[0][1], T[1][1]);
      pl32swap(T[2][0], T[3][0]); pl16swap(T[2][0], T[3][0]);
      pl32swap(T[2][1], T[3][1]); pl16swap(T[2][1], T[3][1]);
      ix4 p0 = {(int)T[0][0], (int)T[0][1], (int)T[1][0], (int)T[1][1]};
      ix4 p1 = {(int)T[2][0], (int)T[2][1], (int)T[3][0], (int)T[3][1]};
      sx8 pf0 = *(sx8*)&p0;
      sx8 pf1 = *(sx8*)&p1;

      lacc[s4] = __builtin_amdgcn_mfma_f32_16x16x32_bf16(onesf, pf0, lacc[s4], 0, 0, 0);
      lacc[s4] = __builtin_amdgcn_mfma_f32_16x16x32_bf16(onesf, pf1, lacc[s4], 0, 0, 0);
      #pragma unroll
      for (int dt = 0; dt < 2; ++dt) {
        fx4 a = acc[s4][dt];
        a = __builtin_amdgcn_mfma_f32_16x16x32_bf16(vf[dt][0], pf0, a, 0, 0, 0);
        a = __builtin_amdgcn_mfma_f32_16x16x32_bf16(vf[dt][1], pf1, a, 0, 0, 0);
        acc[s4][dt] = a;
      }
    }

    // write prefetched next tile into the idle buffer, then ONE barrier
    if (more) {
      *(sx8*)&kts[cur ^ 1][srow * 32 + ksw] = kpre;
      *(sx8*)&vss[cur ^ 1][vblk][vrow * 36 + vg] = vpre;
    }
    __syncthreads();
    cur ^= 1;
  }

  // epilogue: l for this lane's query column is lacc[s4][0] (all rows equal)
  #pragma unroll
  for (int s4 = 0; s4 < 4; ++s4) {
    float inv = 1.f / lacc[s4][0];
    int col = m0 + w * 64 + s4 * 16 + ml;
    #pragma unroll
    for (int dt = 0; dt < 2; ++dt) {
      short tmp[4];
      #pragma unroll
      for (int r = 0; r < 4; ++r) tmp[r] = fbs(acc[s4][dt][r] * inv);
      *(sx4*)(attoT + ((size_t)z * N_ + col) * C_ + h * D_ + dt * 16 + Q4) =
          *(sx4*)tmp;
    }
  }
}

// ---------------------------------------------------------------------------
// Kernel 3: out_proj as MFMA GEMM. D = Wo * (attS + attF), residuals fused.
// ---------------------------------------------------------------------------
__global__ __launch_bounds__(256)
void out_proj_kernel(const bf16* __restrict__ wob, const bf16* __restrict__ attoT,
                     const float* __restrict__ spatial,
                     const float* __restrict__ freq,
                     const float* __restrict__ bo, float* __restrict__ out) {
  const int tid = threadIdx.x;
  const int p0 = blockIdx.x * 128;
  const int o0 = blockIdx.y * 64;
  const int b  = blockIdx.z;

  const int lane = tid & 63, w = tid >> 6;
  const int ml = lane & 15, Q4 = (lane >> 4) * 4, Q8 = (lane >> 4) * 8;
  const int ow = (w >> 1) * 32, pw = (w & 1) * 64;

  __shared__ __align__(16) short asb[64 * 72];
  __shared__ __align__(16) short bsb[128 * 72];
  __shared__ float bo_s[64];

  if (tid < 64) bo_s[tid] = 2.f * bo[o0 + tid];

  const bf16* at0 = attoT + (size_t)(0 + b) * N_ * C_;   // s=0 slice
  const bf16* at1 = attoT + (size_t)(2 + b) * N_ * C_;   // s=1 slice

  const fx4 z4 = {0.f, 0.f, 0.f, 0.f};
  fx4 acc[2][4];
  #pragma unroll
  for (int ot = 0; ot < 2; ++ot)
    #pragma unroll
    for (int pt = 0; pt < 4; ++pt) acc[ot][pt] = z4;

  for (int k0 = 0; k0 < 256; k0 += 64) {
    __syncthreads();
    #pragma unroll
    for (int i = 0; i < 2; ++i) {
      int j = tid + 256 * i;            // 0..511
      int r = j >> 3, cu = (j & 7) * 8;
      *(sx8*)&asb[r * 72 + cu] = *(const sx8*)&wob[(o0 + r) * 256 + k0 + cu];
    }
    #pragma unroll
    for (int i = 0; i < 4; ++i) {
      int j = tid + 256 * i;            // 0..1023
      int p = j >> 3, cu = (j & 7) * 8;
      sx8 va = *(const sx8*)(at0 + (size_t)(p0 + p) * C_ + k0 + cu);
      sx8 vb2 = *(const sx8*)(at1 + (size_t)(p0 + p) * C_ + k0 + cu);
      short tmp[8];
      #pragma unroll
      for (int u = 0; u < 8; ++u) tmp[u] = fbs(sbf(va[u]) + sbf(vb2[u]));
      *(sx8*)&bsb[p * 72 + cu] = *(sx8*)tmp;
    }
    __syncthreads();
    #pragma unroll
    for (int kk = 0; kk < 2; ++kk) {
      sx8 af[2], bfr[4];
      #pragma unroll
      for (int t = 0; t < 2; ++t)
        af[t] = *(sx8*)&asb[(ow + t * 16 + ml) * 72 + kk * 32 + Q8];
      #pragma unroll
      for (int t = 0; t < 4; ++t)
        bfr[t] = *(sx8*)&bsb[(pw + t * 16 + ml) * 72 + kk * 32 + Q8];
      #pragma unroll
      for (int ot = 0; ot < 2; ++ot)
        #pragma unroll
        for (int pt = 0; pt < 4; ++pt)
          acc[ot][pt] = __builtin_amdgcn_mfma_f32_16x16x32_bf16(
              af[ot], bfr[pt], acc[ot][pt], 0, 0, 0);
    }
  }

  #pragma unroll
  for (int ot = 0; ot < 2; ++ot)
    #pragma unroll
    for (int pt = 0; pt < 4; ++pt) {
      int p = p0 + pw + pt * 16 + ml;
      #pragma unroll
      for (int r = 0; r < 4; ++r) {
        int ol = ow + ot * 16 + Q4 + r;
        size_t off = ((size_t)b * C_ + o0 + ol) * N_ + p;
        out[off] = acc[ot][pt][r] + bo_s[ol] + spatial[off] + freq[off];
      }
    }
}

extern "C" void kernel_launch(void* const* d_in, const int* in_sizes, int n_in,
                              void* d_out, int out_size, void* d_ws, size_t ws_size,
                              hipStream_t stream) {
  const float* spatial = (const float*)d_in[0];
  const float* freq    = (const float*)d_in[1];
  const float* wq = (const float*)d_in[2];
  const float* bq = (const float*)d_in[3];
  const float* wk = (const float*)d_in[4];
  const float* bk = (const float*)d_in[5];
  const float* wv = (const float*)d_in[6];
  const float* bv = (const float*)d_in[7];
  const float* wo = (const float*)d_in[8];
  const float* bo = (const float*)d_in[9];
  float* out = (float*)d_out;

  // workspace layout (bf16 elements)
  const size_t SZ = (size_t)2 * B_ * N_ * C_;   // 4.19M elems = 8.4 MB
  bf16* xb    = (bf16*)d_ws;                    // [z][p][c]
  bf16* qhf   = xb + SZ;                        // [z][h][n][d]
  bf16* khf   = qhf + SZ;                       // [z][h][n][d]
  bf16* vhf   = khf + SZ;                       // [z][h] frag-blocked
  bf16* attoT = vhf + SZ;                       // [z][p][c]
  bf16* wb    = attoT + SZ;                     // [768][256]
  bf16* wob   = wb + 768 * 256;                 // [256][256]

  convert_kernel<<<dim3(N_ / 64, C_ / 64, 5), 256, 0, stream>>>(
      spatial, freq, wq, wk, wv, wo, xb, wb, wob);
  qkv_gemm_kernel<<<dim3(N_ / 128, 768 / 128, 2 * B_), 256, 0, stream>>>(
      wb, xb, bq, bk, bv, qhf, khf, vhf);
  attn_kernel<<<dim3(N_ / 256, NH_, 2 * B_), 256, 0, stream>>>(
      qhf, khf, vhf, attoT);
  out_proj_kernel<<<dim3(N_ / 128, C_ / 64, B_), 256, 0, stream>>>(
      wob, attoT, spatial, freq, bo, out);
}

// Round 15
// 203.983 us; speedup vs baseline: 10.0797x; 1.0071x over previous
//
#include <hip/hip_runtime.h>
#include <hip/hip_bf16.h>

#define B_ 2
#define C_ 256
#define NH_ 8
#define D_ 32
#define N_ 4096
#define SCALE_ 0.17677669529663689f
// SCALE * log2(e): folded into Q so softmax is a bare v_exp_f32 per score
#define QSC_ 0.25505277f

typedef __hip_bfloat16 bf16;
typedef __attribute__((ext_vector_type(8))) short sx8;   // 8 bf16 = one MFMA A/B frag
typedef __attribute__((ext_vector_type(4))) short sx4;
typedef __attribute__((ext_vector_type(4))) float fx4;   // MFMA C/D frag
typedef __attribute__((ext_vector_type(4))) int ix4;

__device__ __forceinline__ float b2f(bf16 x) { return __bfloat162float(x); }
__device__ __forceinline__ bf16 f2b(float x) { return __float2bfloat16(x); }
__device__ __forceinline__ short fbs(float x) { bf16 h = __float2bfloat16(x); return *(short*)&h; }
__device__ __forceinline__ float sbf(short s) { bf16 h = *(bf16*)&s; return __bfloat162float(h); }

#if __has_builtin(__builtin_amdgcn_exp2f)
__device__ __forceinline__ float fexp2(float x) { return __builtin_amdgcn_exp2f(x); }
#else
__device__ __forceinline__ float fexp2(float x) { return exp2f(x); }
#endif

// pack two f32 -> one dword of two bf16 by TRUNCATION (1 VALU op via v_perm).
// P in (0,1]; l sums the same truncated values so normalization cancels bias.
__device__ __forceinline__ unsigned pkbf_tr(float x, float y) {
#if __has_builtin(__builtin_amdgcn_perm)
  return __builtin_amdgcn_perm(__builtin_bit_cast(unsigned, y),
                               __builtin_bit_cast(unsigned, x), 0x07060302u);
#else
  unsigned a = __builtin_bit_cast(unsigned, x) >> 16;
  unsigned b = __builtin_bit_cast(unsigned, y) & 0xFFFF0000u;
  return a | b;
#endif
}
// gfx950 MFMA-transpose swaps (VALU cross-lane, not DS pipe) — validated R10
__device__ __forceinline__ void pl32swap(unsigned &a, unsigned &b) {
  asm volatile("v_permlane32_swap_b32 %0, %1" : "+v"(a), "+v"(b));
}
__device__ __forceinline__ void pl16swap(unsigned &a, unsigned &b) {
  asm volatile("v_permlane16_swap_b32 %0, %1" : "+v"(a), "+v"(b));
}

// ---------------------------------------------------------------------------
// Prep (merged): z<4 -> x transpose+convert to xb[z][p][c];
//                z==4 -> weights -> bf16 (wb stacked [wq;wk;wv], wob).
// grid (N_/64, C_/64, 5), block 256
// ---------------------------------------------------------------------------
__global__ __launch_bounds__(256)
void convert_kernel(const float* __restrict__ spatial,
                    const float* __restrict__ freq,
                    const float* __restrict__ wq, const float* __restrict__ wk,
                    const float* __restrict__ wv, const float* __restrict__ wo,
                    bf16* __restrict__ xb, bf16* __restrict__ wb,
                    bf16* __restrict__ wob) {
  const int tid = threadIdx.x;
  if (blockIdx.z == 4) {
    int base = (blockIdx.y * 64 + blockIdx.x) * 256 + tid;   // 0..65535
    #pragma unroll
    for (int i = 0; i < 4; ++i) {
      int idx = base + i * 65536;                            // 0..262143
      if (idx < 196608) {
        const float* src = (idx < 65536) ? wq : (idx < 131072) ? wk : wv;
        wb[idx] = f2b(src[idx & 65535]);
      } else {
        wob[idx - 196608] = f2b(wo[idx - 196608]);
      }
    }
    return;
  }

  const int p0 = blockIdx.x * 64;
  const int c0 = blockIdx.y * 64;
  const int z  = blockIdx.z;            // s*B_ + b
  const int s = z >> 1, b = z & 1;
  const float* x = (s == 0) ? spatial : freq;

  __shared__ float ls[64][65];

  const int pp = tid & 63, cb = tid >> 6;
  #pragma unroll
  for (int i = 0; i < 16; ++i) {
    int c = cb + 4 * i;
    ls[c][pp] = x[(size_t)(b * C_ + c0 + c) * N_ + p0 + pp];
  }
  __syncthreads();

  #pragma unroll
  for (int i = 0; i < 2; ++i) {
    int j = tid + 256 * i;              // 0..511
    int p = j >> 3, ck = (j & 7) * 8;
    short tmp[8];
    #pragma unroll
    for (int u = 0; u < 8; ++u) tmp[u] = fbs(ls[ck + u][p]);
    *(sx8*)(xb + ((size_t)z * N_ + p0 + p) * C_ + c0 + ck) = *(sx8*)tmp;
  }
}

// ---------------------------------------------------------------------------
// Kernel 1: QKV projection as MFMA GEMM. D = W (768x256) * x (256x4096) per z.
//   qhf/khf: per-head pos-major [z][h][n][d32]   (Q pre-scaled by QSC_)
//   vhf:     frag-blocked [z][h][n>>5][d>>4][d&15][n&31]
// grid (N_/128, 768/128, 2*B_), block 256 (4 waves, each 64x64)
// ---------------------------------------------------------------------------
__global__ __launch_bounds__(256)
void qkv_gemm_kernel(const bf16* __restrict__ wb, const bf16* __restrict__ xb,
                     const float* __restrict__ bq, const float* __restrict__ bk,
                     const float* __restrict__ bv,
                     bf16* __restrict__ qhf, bf16* __restrict__ khf,
                     bf16* __restrict__ vhf) {
  const int tid = threadIdx.x;
  const int p0 = blockIdx.x * 128;
  const int o0 = blockIdx.y * 128;
  const int z  = blockIdx.z;

  const int lane = tid & 63, w = tid >> 6;
  const int ml = lane & 15, Q4 = (lane >> 4) * 4, Q8 = (lane >> 4) * 8;
  const int ow = (w >> 1) * 64, pw = (w & 1) * 64;

  __shared__ __align__(16) short asb[128 * 72];
  __shared__ __align__(16) short bsb[128 * 72];
  __shared__ float bias_s[128];

  if (tid < 128) {
    int o = o0 + tid;
    bias_s[tid] = (o < 256) ? bq[o] : (o < 512) ? bk[o - 256] : bv[o - 512];
  }

  const fx4 z4 = {0.f, 0.f, 0.f, 0.f};
  fx4 acc[4][4];
  #pragma unroll
  for (int ot = 0; ot < 4; ++ot)
    #pragma unroll
    for (int pt = 0; pt < 4; ++pt) acc[ot][pt] = z4;

  const int sr = tid >> 1, scu = (tid & 1) * 32;
  for (int k0 = 0; k0 < 256; k0 += 64) {
    __syncthreads();
    #pragma unroll
    for (int u = 0; u < 4; ++u) {
      *(sx8*)&asb[sr * 72 + scu + u * 8] =
          *(const sx8*)&wb[(o0 + sr) * 256 + k0 + scu + u * 8];
      *(sx8*)&bsb[sr * 72 + scu + u * 8] =
          *(const sx8*)(xb + ((size_t)z * N_ + p0 + sr) * C_ + k0 + scu + u * 8);
    }
    __syncthreads();
    #pragma unroll
    for (int kk = 0; kk < 2; ++kk) {
      sx8 af[4], bfr[4];
      #pragma unroll
      for (int t = 0; t < 4; ++t)
        af[t] = *(sx8*)&asb[(ow + t * 16 + ml) * 72 + kk * 32 + Q8];
      #pragma unroll
      for (int t = 0; t < 4; ++t)
        bfr[t] = *(sx8*)&bsb[(pw + t * 16 + ml) * 72 + kk * 32 + Q8];
      #pragma unroll
      for (int ot = 0; ot < 4; ++ot)
        #pragma unroll
        for (int pt = 0; pt < 4; ++pt)
          acc[ot][pt] = __builtin_amdgcn_mfma_f32_16x16x32_bf16(
              af[ot], bfr[pt], acc[ot][pt], 0, 0, 0);
    }
  }

  if (o0 < 512) {
    bf16* dst = (o0 < 256) ? qhf : khf;
    const int ob = (o0 < 256) ? o0 : o0 - 256;
    const float scl = (o0 < 256) ? QSC_ : 1.f;
    #pragma unroll
    for (int ot = 0; ot < 4; ++ot) {
      const int og = ob + ow + ot * 16 + Q4;    // global o, head = og>>5
      #pragma unroll
      for (int pt = 0; pt < 4; ++pt) {
        int p = p0 + pw + pt * 16 + ml;
        short tmp[4];
        #pragma unroll
        for (int r = 0; r < 4; ++r)
          tmp[r] = fbs((acc[ot][pt][r] + bias_s[ow + ot * 16 + Q4 + r]) * scl);
        *(sx4*)(dst + (((size_t)z * NH_ + (og >> 5)) * N_ + p) * D_ + (og & 31)) =
            *(sx4*)tmp;
      }
    }
  } else {
    #pragma unroll
    for (int ot = 0; ot < 4; ++ot)
      #pragma unroll
      for (int pt = 0; pt < 4; ++pt) {
        int p = p0 + pw + pt * 16 + ml;
        #pragma unroll
        for (int r = 0; r < 4; ++r) {
          int lo = ow + ot * 16 + Q4 + r;       // local o in [0,128)
          int rho = (o0 - 512) + lo;            // 0..255
          int h = rho >> 5, d = rho & 31;
          size_t basev = ((size_t)z * NH_ + h) * D_ * N_;
          vhf[basev + (size_t)(((p >> 5) * 2) + (d >> 4)) * 512 +
              (d & 15) * 32 + (p & 31)] = f2b(acc[ot][pt][r] + bias_s[lo]);
        }
      }
  }
}

// ---------------------------------------------------------------------------
// Kernel 2: MFMA flash attention (R14 shape — plateau at ~111 us across
// Q-tile 128/256 and KV-tile 64/128; VALU-issue + dep-chain bound).
// grid (N_/256, NH_, 4), block 256 (4 waves, 64 q each)
// ---------------------------------------------------------------------------
__global__ __launch_bounds__(256, 2)
void attn_kernel(const bf16* __restrict__ qhf, const bf16* __restrict__ khf,
                 const bf16* __restrict__ vhf, bf16* __restrict__ attoT) {
  const int tid  = threadIdx.x;
  const int m0   = blockIdx.x * 256;
  const int h    = blockIdx.y;
  const int z    = blockIdx.z;          // s*B_ + b
  const int s = z >> 1, b = z & 1;
  const int zo = ((1 - s) << 1) | b;    // kv source

  const bf16* qz = qhf + ((size_t)z  * NH_ + h) * N_ * D_;
  const bf16* kz = khf + ((size_t)zo * NH_ + h) * N_ * D_;
  const bf16* vz = vhf + ((size_t)zo * NH_ + h) * D_ * N_;

  const int lane = tid & 63;
  const int w    = tid >> 6;
  const int ml   = lane & 15;
  const int q4   = lane >> 4;           // quad 0..3
  const int Q4   = q4 * 4;
  const int Q8   = q4 * 8;

  // double-buffered 64-key K/V tiles
  __shared__ __align__(16) short kts[2][64 * 32];       // 8 KB (XOR-swizzled)
  __shared__ __align__(16) short vss[2][4][16 * 36];    // 9 KB

  // Q fragments (B-operand): strip s4 -> row m0 + w*64 + s4*16 + ml
  sx8 qf[4];
  #pragma unroll
  for (int s4 = 0; s4 < 4; ++s4)
    qf[s4] = *(const sx8*)(qz + (size_t)(m0 + w * 64 + s4 * 16 + ml) * D_ + Q8);

  sx8 onesf;                            // bf16 1.0 row for the l-sum MFMA
  #pragma unroll
  for (int u = 0; u < 8; ++u) onesf[u] = (short)0x3F80;

  const fx4 z4 = {0.f, 0.f, 0.f, 0.f};
  fx4 acc[4][2];
  #pragma unroll
  for (int s4 = 0; s4 < 4; ++s4) { acc[s4][0] = z4; acc[s4][1] = z4; }
  fx4 lacc[4] = {z4, z4, z4, z4};

  // staging coords (lane-constant swizzles)
  const int srow = tid >> 2;                              // K: row n 0..63
  const int ksw  = ((tid & 3) ^ (srow & 3)) * 8;          // phys d-granule
  const int vblk = tid >> 6, vrow = (tid >> 2) & 15, vg = (tid & 3) * 8;
  const int kfg  = (q4 ^ (ml & 3)) * 8;                   // kts read granule

  sx8 kpre = *(const sx8*)(kz + (size_t)tid * 8);
  sx8 vpre = *(const sx8*)(vz + (size_t)tid * 8);
  *(sx8*)&kts[0][srow * 32 + ksw] = kpre;
  *(sx8*)&vss[0][vblk][vrow * 36 + vg] = vpre;
  __syncthreads();

  int cur = 0;
  for (int n0 = 0; n0 < N_; n0 += 64) {
    const bool more = (n0 + 64 < N_);
    if (more) {
      kpre = *(const sx8*)(kz + (size_t)(n0 + 64) * D_ + (size_t)tid * 8);
      vpre = *(const sx8*)(vz + (size_t)(n0 + 64) * D_ + (size_t)tid * 8);
    }

    // fragments from LDS (shared across all 4 strips)
    sx8 kf[4], vf[2][2];
    #pragma unroll
    for (int t = 0; t < 4; ++t)
      kf[t] = *(sx8*)&kts[cur][(t * 16 + ml) * 32 + kfg];
    #pragma unroll
    for (int dt = 0; dt < 2; ++dt)
      #pragma unroll
      for (int c = 0; c < 2; ++c)
        vf[dt][c] = *(sx8*)&vss[cur][c * 2 + dt][ml * 36 + Q8];

    // strip loop (STATIC index — keeps acc/qf/lacc in registers)
    #pragma unroll
    for (int s4 = 0; s4 < 4; ++s4) {
      fx4 st[4];
      #pragma unroll
      for (int t = 0; t < 4; ++t)
        st[t] = __builtin_amdgcn_mfma_f32_16x16x32_bf16(kf[t], qf[s4], z4, 0, 0, 0);

      // exp + truncate-pack each tile's 4 values into 2 dwords
      unsigned T[4][2];
      #pragma unroll
      for (int t = 0; t < 4; ++t) {
        float e0 = fexp2(st[t][0]), e1 = fexp2(st[t][1]);
        float e2 = fexp2(st[t][2]), e3 = fexp2(st[t][3]);
        T[t][0] = pkbf_tr(e0, e1);
        T[t][1] = pkbf_tr(e2, e3);
      }
      // in-register C-layout -> B-operand transform (validated R10)
      pl32swap(T[0][0], T[1][0]); pl16swap(T[0][0], T[1][0]);
      pl32swap(T[0][1], T[1][1]); pl16swap(T[0][1], T[1][1]);
      pl32swap(T[2][0], T[3][0]); pl16swap(T[2][0], T[3][0]);
      pl32swap(T[2][1], T[3][1]); pl16swap(T[2][1], T[3][1]);
      ix4 p0 = {(int)T[0][0], (int)T[0][1], (int)T[1][0], (int)T[1][1]};
      ix4 p1 = {(int)T[2][0], (int)T[2][1], (int)T[3][0], (int)T[3][1]};
      sx8 pf0 = *(sx8*)&p0;
      sx8 pf1 = *(sx8*)&p1;

      lacc[s4] = __builtin_amdgcn_mfma_f32_16x16x32_bf16(onesf, pf0, lacc[s4], 0, 0, 0);
      lacc[s4] = __builtin_amdgcn_mfma_f32_16x16x32_bf16(onesf, pf1, lacc[s4], 0, 0, 0);
      #pragma unroll
      for (int dt = 0; dt < 2; ++dt) {
        fx4 a = acc[s4][dt];
        a = __builtin_amdgcn_mfma_f32_16x16x32_bf16(vf[dt][0], pf0, a, 0, 0, 0);
        a = __builtin_amdgcn_mfma_f32_16x16x32_bf16(vf[dt][1], pf1, a, 0, 0, 0);
        acc[s4][dt] = a;
      }
    }

    // write prefetched next tile into the idle buffer, then ONE barrier
    if (more) {
      *(sx8*)&kts[cur ^ 1][srow * 32 + ksw] = kpre;
      *(sx8*)&vss[cur ^ 1][vblk][vrow * 36 + vg] = vpre;
    }
    __syncthreads();
    cur ^= 1;
  }

  // epilogue: l for this lane's query column is lacc[s4][0] (all rows equal)
  #pragma unroll
  for (int s4 = 0; s4 < 4; ++s4) {
    float inv = 1.f / lacc[s4][0];
    int col = m0 + w * 64 + s4 * 16 + ml;
    #pragma unroll
    for (int dt = 0; dt < 2; ++dt) {
      short tmp[4];
      #pragma unroll
      for (int r = 0; r < 4; ++r) tmp[r] = fbs(acc[s4][dt][r] * inv);
      *(sx4*)(attoT + ((size_t)z * N_ + col) * C_ + h * D_ + dt * 16 + Q4) =
          *(sx4*)tmp;
    }
  }
}

// ---------------------------------------------------------------------------
// Kernel 3: out_proj as MFMA GEMM. D = Wo * (attS + attF), residuals fused.
// p-tile 64 -> grid 512 blocks = 2/CU (was 256 = 1/CU, occupancy-starved).
// grid (N_/64, 256/64, B_), block 256 (4 waves, each 32x32)
// ---------------------------------------------------------------------------
__global__ __launch_bounds__(256)
void out_proj_kernel(const bf16* __restrict__ wob, const bf16* __restrict__ attoT,
                     const float* __restrict__ spatial,
                     const float* __restrict__ freq,
                     const float* __restrict__ bo, float* __restrict__ out) {
  const int tid = threadIdx.x;
  const int p0 = blockIdx.x * 64;
  const int o0 = blockIdx.y * 64;
  const int b  = blockIdx.z;

  const int lane = tid & 63, w = tid >> 6;
  const int ml = lane & 15, Q4 = (lane >> 4) * 4, Q8 = (lane >> 4) * 8;
  const int ow = (w >> 1) * 32, pw = (w & 1) * 32;

  __shared__ __align__(16) short asb[64 * 72];
  __shared__ __align__(16) short bsb[64 * 72];
  __shared__ float bo_s[64];

  if (tid < 64) bo_s[tid] = 2.f * bo[o0 + tid];

  const bf16* at0 = attoT + (size_t)(0 + b) * N_ * C_;   // s=0 slice
  const bf16* at1 = attoT + (size_t)(2 + b) * N_ * C_;   // s=1 slice

  const fx4 z4 = {0.f, 0.f, 0.f, 0.f};
  fx4 acc[2][2];
  #pragma unroll
  for (int ot = 0; ot < 2; ++ot)
    #pragma unroll
    for (int pt = 0; pt < 2; ++pt) acc[ot][pt] = z4;

  for (int k0 = 0; k0 < 256; k0 += 64) {
    __syncthreads();
    #pragma unroll
    for (int i = 0; i < 2; ++i) {
      int j = tid + 256 * i;            // 0..511
      int r = j >> 3, cu = (j & 7) * 8;
      *(sx8*)&asb[r * 72 + cu] = *(const sx8*)&wob[(o0 + r) * 256 + k0 + cu];
      sx8 va = *(const sx8*)(at0 + (size_t)(p0 + r) * C_ + k0 + cu);
      sx8 vb2 = *(const sx8*)(at1 + (size_t)(p0 + r) * C_ + k0 + cu);
      short tmp[8];
      #pragma unroll
      for (int u = 0; u < 8; ++u) tmp[u] = fbs(sbf(va[u]) + sbf(vb2[u]));
      *(sx8*)&bsb[r * 72 + cu] = *(sx8*)tmp;
    }
    __syncthreads();
    #pragma unroll
    for (int kk = 0; kk < 2; ++kk) {
      sx8 af[2], bfr[2];
      #pragma unroll
      for (int t = 0; t < 2; ++t)
        af[t] = *(sx8*)&asb[(ow + t * 16 + ml) * 72 + kk * 32 + Q8];
      #pragma unroll
      for (int t = 0; t < 2; ++t)
        bfr[t] = *(sx8*)&bsb[(pw + t * 16 + ml) * 72 + kk * 32 + Q8];
      #pragma unroll
      for (int ot = 0; ot < 2; ++ot)
        #pragma unroll
        for (int pt = 0; pt < 2; ++pt)
          acc[ot][pt] = __builtin_amdgcn_mfma_f32_16x16x32_bf16(
              af[ot], bfr[pt], acc[ot][pt], 0, 0, 0);
    }
  }

  #pragma unroll
  for (int ot = 0; ot < 2; ++ot)
    #pragma unroll
    for (int pt = 0; pt < 2; ++pt) {
      int p = p0 + pw + pt * 16 + ml;
      #pragma unroll
      for (int r = 0; r < 4; ++r) {
        int ol = ow + ot * 16 + Q4 + r;
        size_t off = ((size_t)b * C_ + o0 + ol) * N_ + p;
        out[off] = acc[ot][pt][r] + bo_s[ol] + spatial[off] + freq[off];
      }
    }
}

extern "C" void kernel_launch(void* const* d_in, const int* in_sizes, int n_in,
                              void* d_out, int out_size, void* d_ws, size_t ws_size,
                              hipStream_t stream) {
  const float* spatial = (const float*)d_in[0];
  const float* freq    = (const float*)d_in[1];
  const float* wq = (const float*)d_in[2];
  const float* bq = (const float*)d_in[3];
  const float* wk = (const float*)d_in[4];
  const float* bk = (const float*)d_in[5];
  const float* wv = (const float*)d_in[6];
  const float* bv = (const float*)d_in[7];
  const float* wo = (const float*)d_in[8];
  const float* bo = (const float*)d_in[9];
  float* out = (float*)d_out;

  // workspace layout (bf16 elements)
  const size_t SZ = (size_t)2 * B_ * N_ * C_;   // 4.19M elems = 8.4 MB
  bf16* xb    = (bf16*)d_ws;                    // [z][p][c]
  bf16* qhf   = xb + SZ;                        // [z][h][n][d]
  bf16* khf   = qhf + SZ;                       // [z][h][n][d]
  bf16* vhf   = khf + SZ;                       // [z][h] frag-blocked
  bf16* attoT = vhf + SZ;                       // [z][p][c]
  bf16* wb    = attoT + SZ;                     // [768][256]
  bf16* wob   = wb + 768 * 256;                 // [256][256]

  convert_kernel<<<dim3(N_ / 64, C_ / 64, 5), 256, 0, stream>>>(
      spatial, freq, wq, wk, wv, wo, xb, wb, wob);
  qkv_gemm_kernel<<<dim3(N_ / 128, 768 / 128, 2 * B_), 256, 0, stream>>>(
      wb, xb, bq, bk, bv, qhf, khf, vhf);
  attn_kernel<<<dim3(N_ / 256, NH_, 2 * B_), 256, 0, stream>>>(
      qhf, khf, vhf, attoT);
  out_proj_kernel<<<dim3(N_ / 64, C_ / 64, B_), 256, 0, stream>>>(
      wob, attoT, spatial, freq, bo, out);
}